// Round 2
// baseline (424.904 us; speedup 1.0000x reference)
//
#include <hip/hip_runtime.h>
#include <math.h>

#define M_SLOTS 60
#define B_SZ    64
#define C_CH    256
#define HW      3136          // 56*56
#define POS     (C_CH * HW)   // 802816 positions per memory slot / per batch
#define EPS     1e-8f
#define B_TILE  16            // batches per wave in wsum

// ---------------------------------------------------------------------------
// Kernel A: per-(m,c) row sum of 3136 spatial elements. One wave per row.
// grid = 15360/4 blocks, block = 256 (4 waves, 1 row each). ~BW-bound, ~35 us.
// ---------------------------------------------------------------------------
__global__ __launch_bounds__(256) void avg_kernel(const float* __restrict__ pool,
                                                  float* __restrict__ sums) {
    const int row  = blockIdx.x * 4 + (threadIdx.x >> 6);  // [0, 15360)
    const int lane = threadIdx.x & 63;
    const float4* r4 = (const float4*)(pool + (size_t)row * HW);  // 12544 B rows, 16B-aligned
    float s = 0.0f;
    for (int i = lane; i < HW / 4; i += 64) {   // 784 float4 per row
        float4 v = r4[i];
        s += v.x + v.y + v.z + v.w;
    }
    #pragma unroll
    for (int off = 32; off; off >>= 1) s += __shfl_down(s, off);
    if (lane == 0) sums[row] = s;
}

// ---------------------------------------------------------------------------
// Kernel B: cosine sim + softmax. grid = 64 (one block per b), block = 256.
// Writes transposed weights wT[m*64 + b]. Tiny (~3 us).
// ---------------------------------------------------------------------------
__global__ __launch_bounds__(256) void weights_kernel(const float* __restrict__ q,
                                                      const float* __restrict__ sums,
                                                      float* __restrict__ wT) {
    const int b    = blockIdx.x;
    const int wave = threadIdx.x >> 6;
    const int lane = threadIdx.x & 63;
    const float inv = 1.0f / (float)HW;

    __shared__ float s_cos[M_SLOTS];

    // each lane holds 4 channels of q[b]; each wave computes qn redundantly (no sync needed)
    float4 qv = ((const float4*)(q + b * C_CH))[lane];
    float qn2 = qv.x*qv.x + qv.y*qv.y + qv.z*qv.z + qv.w*qv.w;
    #pragma unroll
    for (int off = 32; off; off >>= 1) qn2 += __shfl_down(qn2, off);
    qn2 = __shfl(qn2, 0);
    const float qn = fmaxf(sqrtf(qn2), EPS);

    // waves split the 60 memory slots
    for (int m = wave; m < M_SLOTS; m += 4) {
        float4 mv = ((const float4*)(sums + m * C_CH))[lane];
        mv.x *= inv; mv.y *= inv; mv.z *= inv; mv.w *= inv;
        float dot = qv.x*mv.x + qv.y*mv.y + qv.z*mv.z + qv.w*mv.w;
        float mn2 = mv.x*mv.x + mv.y*mv.y + mv.z*mv.z + mv.w*mv.w;
        #pragma unroll
        for (int off = 32; off; off >>= 1) {
            dot += __shfl_down(dot, off);
            mn2 += __shfl_down(mn2, off);
        }
        if (lane == 0) {
            float mn = fmaxf(sqrtf(mn2), EPS);
            s_cos[m] = dot / (qn * mn);
        }
    }
    __syncthreads();

    if (wave == 0) {
        float c = (lane < M_SLOTS) ? s_cos[lane] : -INFINITY;
        float mx = c;
        #pragma unroll
        for (int off = 32; off; off >>= 1) mx = fmaxf(mx, __shfl_down(mx, off));
        mx = __shfl(mx, 0);
        float e = (lane < M_SLOTS) ? __expf(c - mx) : 0.0f;
        float sum = e;
        #pragma unroll
        for (int off = 32; off; off >>= 1) sum += __shfl_down(sum, off);
        sum = __shfl(sum, 0);
        if (lane < M_SLOTS) wT[lane * B_SZ + b] = e / sum;
    }
}

// ---------------------------------------------------------------------------
// Kernel C v2: weighted sum, restructured.
//  - block = 256 (4 waves); wave w owns batches [16w, 16w+16)  -> acc[16] float4
//  - each thread processes ONE float4 (4 positions): 16B vector load AND store
//  - all 4 waves read the SAME pool lines -> L1/L2 intra-block reuse
//  - weights staged in LDS once; per-m fetch = 4x ds_read_b128 broadcast
//    (uniform address, conflict-free), 4 LDS reads : 64 FMAs
//  - pool's 2nd pass largely hits Infinity Cache (192.7 MB < 256 MB, warmed by avg)
// grid = POS/256 = 3136 blocks (each block covers 64 float4 = 256 positions).
// ---------------------------------------------------------------------------
__global__ __launch_bounds__(256) void wsum_kernel(const float* __restrict__ pool,
                                                   const float* __restrict__ wT,
                                                   float* __restrict__ out) {
    __shared__ float s_w[M_SLOTS * B_SZ];   // 15360 B

    #pragma unroll
    for (int i = threadIdx.x; i < M_SLOTS * B_SZ; i += 256)
        s_w[i] = wT[i];
    __syncthreads();

    const int wave = threadIdx.x >> 6;
    const int lane = threadIdx.x & 63;
    const int b0   = wave * B_TILE;
    const size_t pos4 = (size_t)blockIdx.x * 64 + lane;   // float4 index within a plane

    const float4* p4 = (const float4*)pool;
    float4*       o4 = (float4*)out;

    float4 acc[B_TILE];
    #pragma unroll
    for (int j = 0; j < B_TILE; ++j) acc[j] = make_float4(0.f, 0.f, 0.f, 0.f);

    #pragma unroll 2
    for (int m = 0; m < M_SLOTS; ++m) {
        const float4 p = p4[(size_t)m * (POS / 4) + pos4];           // 16B coalesced load
        const float4* wrow = (const float4*)(s_w + m * B_SZ + b0);   // 16B-aligned, uniform addr
        #pragma unroll
        for (int q = 0; q < B_TILE / 4; ++q) {
            const float4 wv = wrow[q];                               // ds_read_b128 broadcast
            const int j = q * 4;
            acc[j+0].x = fmaf(wv.x, p.x, acc[j+0].x);
            acc[j+0].y = fmaf(wv.x, p.y, acc[j+0].y);
            acc[j+0].z = fmaf(wv.x, p.z, acc[j+0].z);
            acc[j+0].w = fmaf(wv.x, p.w, acc[j+0].w);
            acc[j+1].x = fmaf(wv.y, p.x, acc[j+1].x);
            acc[j+1].y = fmaf(wv.y, p.y, acc[j+1].y);
            acc[j+1].z = fmaf(wv.y, p.z, acc[j+1].z);
            acc[j+1].w = fmaf(wv.y, p.w, acc[j+1].w);
            acc[j+2].x = fmaf(wv.z, p.x, acc[j+2].x);
            acc[j+2].y = fmaf(wv.z, p.y, acc[j+2].y);
            acc[j+2].z = fmaf(wv.z, p.z, acc[j+2].z);
            acc[j+2].w = fmaf(wv.z, p.w, acc[j+2].w);
            acc[j+3].x = fmaf(wv.w, p.x, acc[j+3].x);
            acc[j+3].y = fmaf(wv.w, p.y, acc[j+3].y);
            acc[j+3].z = fmaf(wv.w, p.z, acc[j+3].z);
            acc[j+3].w = fmaf(wv.w, p.w, acc[j+3].w);
        }
    }

    #pragma unroll
    for (int j = 0; j < B_TILE; ++j) {
        o4[(size_t)(b0 + j) * (POS / 4) + pos4] = acc[j];            // 16B coalesced store
    }
}

// ---------------------------------------------------------------------------
extern "C" void kernel_launch(void* const* d_in, const int* in_sizes, int n_in,
                              void* d_out, int out_size, void* d_ws, size_t ws_size,
                              hipStream_t stream) {
    const float* pool = (const float*)d_in[0];   // [60,256,56,56]
    const float* q    = (const float*)d_in[1];   // [64,256]
    float* out        = (float*)d_out;           // [64,256,56,56]

    float* sums = (float*)d_ws;                              // 60*256 floats = 61440 B
    float* wT   = (float*)((char*)d_ws + M_SLOTS * C_CH * sizeof(float));  // 60*64 floats

    avg_kernel<<<(M_SLOTS * C_CH) / 4, 256, 0, stream>>>(pool, sums);
    weights_kernel<<<B_SZ, 256, 0, stream>>>(q, sums, wT);
    wsum_kernel<<<POS / 256, 256, 0, stream>>>(pool, wT, out);
}

// Round 3
// 401.256 us; speedup vs baseline: 1.0589x; 1.0589x over previous
//
#include <hip/hip_runtime.h>
#include <math.h>

#define M_SLOTS 60
#define B_SZ    64
#define C_CH    256
#define HW      3136          // 56*56
#define POS     (C_CH * HW)   // 802816 positions per memory slot / per batch
#define EPS     1e-8f
#define B_TILE  16            // batches per wave in wsum

typedef float f32x4 __attribute__((ext_vector_type(4)));

// ---------------------------------------------------------------------------
// Kernel A: per-(m,c) row sum of 3136 spatial elements. One wave per row.
// grid = 15360/4 blocks, block = 256 (4 waves, 1 row each).
// Normal (caching) loads on purpose: this pass warms the 256MB L3 with pool
// (192.7 MB) so wsum's second pass reads from LLC instead of HBM.
// ---------------------------------------------------------------------------
__global__ __launch_bounds__(256) void avg_kernel(const float* __restrict__ pool,
                                                  float* __restrict__ sums) {
    const int row  = blockIdx.x * 4 + (threadIdx.x >> 6);  // [0, 15360)
    const int lane = threadIdx.x & 63;
    const float4* r4 = (const float4*)(pool + (size_t)row * HW);  // 12544 B rows, 16B-aligned
    float s = 0.0f;
    for (int i = lane; i < HW / 4; i += 64) {   // 784 float4 per row
        float4 v = r4[i];
        s += v.x + v.y + v.z + v.w;
    }
    #pragma unroll
    for (int off = 32; off; off >>= 1) s += __shfl_down(s, off);
    if (lane == 0) sums[row] = s;
}

// ---------------------------------------------------------------------------
// Kernel B: cosine sim + softmax. grid = 64 (one block per b), block = 256.
// Writes transposed weights wT[m*64 + b]. Tiny (~5 us).
// ---------------------------------------------------------------------------
__global__ __launch_bounds__(256) void weights_kernel(const float* __restrict__ q,
                                                      const float* __restrict__ sums,
                                                      float* __restrict__ wT) {
    const int b    = blockIdx.x;
    const int wave = threadIdx.x >> 6;
    const int lane = threadIdx.x & 63;
    const float inv = 1.0f / (float)HW;

    __shared__ float s_cos[M_SLOTS];

    // each lane holds 4 channels of q[b]; each wave computes qn redundantly (no sync needed)
    float4 qv = ((const float4*)(q + b * C_CH))[lane];
    float qn2 = qv.x*qv.x + qv.y*qv.y + qv.z*qv.z + qv.w*qv.w;
    #pragma unroll
    for (int off = 32; off; off >>= 1) qn2 += __shfl_down(qn2, off);
    qn2 = __shfl(qn2, 0);
    const float qn = fmaxf(sqrtf(qn2), EPS);

    // waves split the 60 memory slots
    for (int m = wave; m < M_SLOTS; m += 4) {
        float4 mv = ((const float4*)(sums + m * C_CH))[lane];
        mv.x *= inv; mv.y *= inv; mv.z *= inv; mv.w *= inv;
        float dot = qv.x*mv.x + qv.y*mv.y + qv.z*mv.z + qv.w*mv.w;
        float mn2 = mv.x*mv.x + mv.y*mv.y + mv.z*mv.z + mv.w*mv.w;
        #pragma unroll
        for (int off = 32; off; off >>= 1) {
            dot += __shfl_down(dot, off);
            mn2 += __shfl_down(mn2, off);
        }
        if (lane == 0) {
            float mn = fmaxf(sqrtf(mn2), EPS);
            s_cos[m] = dot / (qn * mn);
        }
    }
    __syncthreads();

    if (wave == 0) {
        float c = (lane < M_SLOTS) ? s_cos[lane] : -INFINITY;
        float mx = c;
        #pragma unroll
        for (int off = 32; off; off >>= 1) mx = fmaxf(mx, __shfl_down(mx, off));
        mx = __shfl(mx, 0);
        float e = (lane < M_SLOTS) ? __expf(c - mx) : 0.0f;
        float sum = e;
        #pragma unroll
        for (int off = 32; off; off >>= 1) sum += __shfl_down(sum, off);
        sum = __shfl(sum, 0);
        if (lane < M_SLOTS) wT[lane * B_SZ + b] = e / sum;
    }
}

// ---------------------------------------------------------------------------
// wsum inner block: 16 batches x 4 positions of FMA for one m.
// acc indices are compile-time after inlining+unroll (no scratch, rule #20).
// ---------------------------------------------------------------------------
__device__ __forceinline__ void fma_block(float4* acc, const float* s_w,
                                          int m, int b0, float4 p) {
    const float4* wrow = (const float4*)(s_w + m * B_SZ + b0);   // uniform addr -> broadcast
    #pragma unroll
    for (int qq = 0; qq < 4; ++qq) {
        const float4 wv = wrow[qq];                              // ds_read_b128, conflict-free
        const int j = qq * 4;
        acc[j+0].x = fmaf(wv.x, p.x, acc[j+0].x);
        acc[j+0].y = fmaf(wv.x, p.y, acc[j+0].y);
        acc[j+0].z = fmaf(wv.x, p.z, acc[j+0].z);
        acc[j+0].w = fmaf(wv.x, p.w, acc[j+0].w);
        acc[j+1].x = fmaf(wv.y, p.x, acc[j+1].x);
        acc[j+1].y = fmaf(wv.y, p.y, acc[j+1].y);
        acc[j+1].z = fmaf(wv.y, p.z, acc[j+1].z);
        acc[j+1].w = fmaf(wv.y, p.w, acc[j+1].w);
        acc[j+2].x = fmaf(wv.z, p.x, acc[j+2].x);
        acc[j+2].y = fmaf(wv.z, p.y, acc[j+2].y);
        acc[j+2].z = fmaf(wv.z, p.z, acc[j+2].z);
        acc[j+2].w = fmaf(wv.z, p.w, acc[j+2].w);
        acc[j+3].x = fmaf(wv.w, p.x, acc[j+3].x);
        acc[j+3].y = fmaf(wv.w, p.y, acc[j+3].y);
        acc[j+3].z = fmaf(wv.w, p.z, acc[j+3].z);
        acc[j+3].w = fmaf(wv.w, p.w, acc[j+3].w);
    }
}

// ---------------------------------------------------------------------------
// Kernel C v3: weighted sum with depth-4 software prefetch + nt stores.
//  - block = 256 (4 waves); wave w owns batches [16w,16w+16) -> acc[16] float4
//  - each thread: ONE float4 (4 positions); all 4 waves share pool lines (L1)
//  - weights staged in LDS once; uniform-address ds_read_b128 broadcasts
//  - prefetch ring of 4 float4 (64 B/thread in flight) hides load latency
//    under 4x64 = 256 FMAs (~512 SIMD32 cycles)
//  - out stored non-temporally: write-once data, keeps pool resident in L3
//    so this kernel's pool reads hit the LLC warmed by avg_kernel
// grid = POS/256 = 3136 blocks.
// ---------------------------------------------------------------------------
__global__ __launch_bounds__(256) void wsum_kernel(const float* __restrict__ pool,
                                                   const float* __restrict__ wT,
                                                   float* __restrict__ out) {
    __shared__ float s_w[M_SLOTS * B_SZ];   // 15360 B

    for (int i = threadIdx.x; i < M_SLOTS * B_SZ; i += 256)
        s_w[i] = wT[i];
    __syncthreads();

    const int wave = threadIdx.x >> 6;
    const int lane = threadIdx.x & 63;
    const int b0   = wave * B_TILE;
    const size_t pos4 = (size_t)blockIdx.x * 64 + lane;   // float4 index within a plane

    const float4* pp = (const float4*)pool + pos4;        // stride POS/4 per m
    float4*       oo = (float4*)out + pos4;               // stride POS/4 per b

    float4 acc[B_TILE];
    #pragma unroll
    for (int j = 0; j < B_TILE; ++j) acc[j] = make_float4(0.f, 0.f, 0.f, 0.f);

    // prime the prefetch ring (m = 0..3)
    float4 pr0 = pp[(size_t)0 * (POS / 4)];
    float4 pr1 = pp[(size_t)1 * (POS / 4)];
    float4 pr2 = pp[(size_t)2 * (POS / 4)];
    float4 pr3 = pp[(size_t)3 * (POS / 4)];

    #pragma unroll 1
    for (int mb = 0; mb + 4 < M_SLOTS; mb += 4) {          // mb = 0,4,...,52
        // issue next 4 loads before consuming current 4 (indices all static-offset)
        const float4 nx0 = pp[(size_t)(mb + 4) * (POS / 4)];
        const float4 nx1 = pp[(size_t)(mb + 5) * (POS / 4)];
        const float4 nx2 = pp[(size_t)(mb + 6) * (POS / 4)];
        const float4 nx3 = pp[(size_t)(mb + 7) * (POS / 4)];
        fma_block(acc, s_w, mb + 0, b0, pr0);
        fma_block(acc, s_w, mb + 1, b0, pr1);
        fma_block(acc, s_w, mb + 2, b0, pr2);
        fma_block(acc, s_w, mb + 3, b0, pr3);
        pr0 = nx0; pr1 = nx1; pr2 = nx2; pr3 = nx3;
    }
    // tail: m = 56..59 already in the ring
    fma_block(acc, s_w, 56, b0, pr0);
    fma_block(acc, s_w, 57, b0, pr1);
    fma_block(acc, s_w, 58, b0, pr2);
    fma_block(acc, s_w, 59, b0, pr3);

    #pragma unroll
    for (int j = 0; j < B_TILE; ++j) {
        // nontemporal 16B store: out is write-once, don't evict pool from L3
        __builtin_nontemporal_store(*(const f32x4*)&acc[j],
                                    (f32x4*)&oo[(size_t)(b0 + j) * (POS / 4)]);
    }
}

// ---------------------------------------------------------------------------
extern "C" void kernel_launch(void* const* d_in, const int* in_sizes, int n_in,
                              void* d_out, int out_size, void* d_ws, size_t ws_size,
                              hipStream_t stream) {
    const float* pool = (const float*)d_in[0];   // [60,256,56,56]
    const float* q    = (const float*)d_in[1];   // [64,256]
    float* out        = (float*)d_out;           // [64,256,56,56]

    float* sums = (float*)d_ws;                              // 60*256 floats = 61440 B
    float* wT   = (float*)((char*)d_ws + M_SLOTS * C_CH * sizeof(float));  // 60*64 floats

    avg_kernel<<<(M_SLOTS * C_CH) / 4, 256, 0, stream>>>(pool, sums);
    weights_kernel<<<B_SZ, 256, 0, stream>>>(q, sums, wT);
    wsum_kernel<<<POS / 256, 256, 0, stream>>>(pool, wT, out);
}

// Round 4
// 395.338 us; speedup vs baseline: 1.0748x; 1.0150x over previous
//
#include <hip/hip_runtime.h>
#include <math.h>

#define M_SLOTS 60
#define B_SZ    64
#define C_CH    256
#define HW      3136          // 56*56
#define POS     (C_CH * HW)   // 802816 positions per memory slot / per batch
#define EPS     1e-8f
#define B_TILE  16            // batches per wave in wsum

typedef float f32x4 __attribute__((ext_vector_type(4)));
typedef float f32x2 __attribute__((ext_vector_type(2)));

// ---------------------------------------------------------------------------
// Kernel A: per-(m,c) row sum of 3136 spatial elements. One wave per row.
// grid = 15360/4 blocks, block = 256 (4 waves, 1 row each). BW-bound ~31 us.
// Normal (caching) loads on purpose: warms L3 with pool (192.7 MB < 256 MB)
// so wsum's second pass reads from LLC instead of HBM.
// ---------------------------------------------------------------------------
__global__ __launch_bounds__(256) void avg_kernel(const float* __restrict__ pool,
                                                  float* __restrict__ sums) {
    const int row  = blockIdx.x * 4 + (threadIdx.x >> 6);  // [0, 15360)
    const int lane = threadIdx.x & 63;
    const float4* r4 = (const float4*)(pool + (size_t)row * HW);  // 12544 B rows, 16B-aligned
    float s = 0.0f;
    for (int i = lane; i < HW / 4; i += 64) {   // 784 float4 per row
        float4 v = r4[i];
        s += v.x + v.y + v.z + v.w;
    }
    #pragma unroll
    for (int off = 32; off; off >>= 1) s += __shfl_down(s, off);
    if (lane == 0) sums[row] = s;
}

// ---------------------------------------------------------------------------
// Kernel B: cosine sim + softmax. grid = 64 (one block per b), block = 256.
// Writes transposed weights wT[m*64 + b]. Tiny (~4 us).
// ---------------------------------------------------------------------------
__global__ __launch_bounds__(256) void weights_kernel(const float* __restrict__ q,
                                                      const float* __restrict__ sums,
                                                      float* __restrict__ wT) {
    const int b    = blockIdx.x;
    const int wave = threadIdx.x >> 6;
    const int lane = threadIdx.x & 63;
    const float inv = 1.0f / (float)HW;

    __shared__ float s_cos[M_SLOTS];

    // each lane holds 4 channels of q[b]; each wave computes qn redundantly (no sync needed)
    float4 qv = ((const float4*)(q + b * C_CH))[lane];
    float qn2 = qv.x*qv.x + qv.y*qv.y + qv.z*qv.z + qv.w*qv.w;
    #pragma unroll
    for (int off = 32; off; off >>= 1) qn2 += __shfl_down(qn2, off);
    qn2 = __shfl(qn2, 0);
    const float qn = fmaxf(sqrtf(qn2), EPS);

    // waves split the 60 memory slots
    for (int m = wave; m < M_SLOTS; m += 4) {
        float4 mv = ((const float4*)(sums + m * C_CH))[lane];
        mv.x *= inv; mv.y *= inv; mv.z *= inv; mv.w *= inv;
        float dot = qv.x*mv.x + qv.y*mv.y + qv.z*mv.z + qv.w*mv.w;
        float mn2 = mv.x*mv.x + mv.y*mv.y + mv.z*mv.z + mv.w*mv.w;
        #pragma unroll
        for (int off = 32; off; off >>= 1) {
            dot += __shfl_down(dot, off);
            mn2 += __shfl_down(mn2, off);
        }
        if (lane == 0) {
            float mn = fmaxf(sqrtf(mn2), EPS);
            s_cos[m] = dot / (qn * mn);
        }
    }
    __syncthreads();

    if (wave == 0) {
        float c = (lane < M_SLOTS) ? s_cos[lane] : -INFINITY;
        float mx = c;
        #pragma unroll
        for (int off = 32; off; off >>= 1) mx = fmaxf(mx, __shfl_down(mx, off));
        mx = __shfl(mx, 0);
        float e = (lane < M_SLOTS) ? __expf(c - mx) : 0.0f;
        float sum = e;
        #pragma unroll
        for (int off = 32; off; off >>= 1) sum += __shfl_down(sum, off);
        sum = __shfl(sum, 0);
        if (lane < M_SLOTS) wT[lane * B_SZ + b] = e / sum;
    }
}

// ---------------------------------------------------------------------------
// wsum inner block for one m: 16 batches x 4 positions, packed fp32 pairs.
// acc2 layout: batch b -> acc2[2b] = positions {0,1}, acc2[2b+1] = {2,3}.
// __builtin_elementwise_fma on f32x2 lowers to v_pk_fma_f32 (VOP3P) on gfx9+:
// halves VALU issue slots (32 pk-fma vs 64 fma); worst case 2 scalar fmas.
// All indices compile-time after unroll (rule #20: no scratch).
// ---------------------------------------------------------------------------
__device__ __forceinline__ void fma_block2(f32x2* acc2, const float* s_w,
                                           int m, int b0, float4 p) {
    const float4* wrow = (const float4*)(s_w + m * B_SZ + b0);   // uniform addr -> broadcast
    f32x2 p01; p01.x = p.x; p01.y = p.y;
    f32x2 p23; p23.x = p.z; p23.y = p.w;
    #pragma unroll
    for (int qq = 0; qq < 4; ++qq) {
        const float4 wv = wrow[qq];                              // ds_read_b128, conflict-free
        const int j = qq * 8;
        f32x2 w0; w0.x = wv.x; w0.y = wv.x;
        f32x2 w1; w1.x = wv.y; w1.y = wv.y;
        f32x2 w2; w2.x = wv.z; w2.y = wv.z;
        f32x2 w3; w3.x = wv.w; w3.y = wv.w;
        acc2[j+0] = __builtin_elementwise_fma(w0, p01, acc2[j+0]);
        acc2[j+1] = __builtin_elementwise_fma(w0, p23, acc2[j+1]);
        acc2[j+2] = __builtin_elementwise_fma(w1, p01, acc2[j+2]);
        acc2[j+3] = __builtin_elementwise_fma(w1, p23, acc2[j+3]);
        acc2[j+4] = __builtin_elementwise_fma(w2, p01, acc2[j+4]);
        acc2[j+5] = __builtin_elementwise_fma(w2, p23, acc2[j+5]);
        acc2[j+6] = __builtin_elementwise_fma(w3, p01, acc2[j+6]);
        acc2[j+7] = __builtin_elementwise_fma(w3, p23, acc2[j+7]);
    }
}

// ---------------------------------------------------------------------------
// Kernel C v4: weighted sum. Depth-4 prefetch ring + packed-fp32 FMA + nt store.
//  - block = 256 (4 waves); wave w owns batches [16w,16w+16) -> acc2[32] (64 VGPR)
//  - each thread: ONE float4 (4 positions); 4 waves share pool lines via L1
//  - weights staged in LDS once; uniform-address ds_read_b128 broadcasts
//  - prefetch ring of 4 float4 (64 B/thread in flight) hides load latency
//  - out stored non-temporally (write-once; keep pool resident in L3)
// grid = POS/256 = 3136 blocks.
// ---------------------------------------------------------------------------
__global__ __launch_bounds__(256) void wsum_kernel(const float* __restrict__ pool,
                                                   const float* __restrict__ wT,
                                                   float* __restrict__ out) {
    __shared__ float s_w[M_SLOTS * B_SZ];   // 15360 B

    for (int i = threadIdx.x; i < M_SLOTS * B_SZ; i += 256)
        s_w[i] = wT[i];
    __syncthreads();

    const int wave = threadIdx.x >> 6;
    const int lane = threadIdx.x & 63;
    const int b0   = wave * B_TILE;
    const size_t pos4 = (size_t)blockIdx.x * 64 + lane;   // float4 index within a plane

    const float4* pp = (const float4*)pool + pos4;        // stride POS/4 per m
    float4*       oo = (float4*)out + pos4;               // stride POS/4 per b

    f32x2 acc2[2 * B_TILE];
    #pragma unroll
    for (int j = 0; j < 2 * B_TILE; ++j) { acc2[j].x = 0.f; acc2[j].y = 0.f; }

    // prime the prefetch ring (m = 0..3)
    float4 pr0 = pp[(size_t)0 * (POS / 4)];
    float4 pr1 = pp[(size_t)1 * (POS / 4)];
    float4 pr2 = pp[(size_t)2 * (POS / 4)];
    float4 pr3 = pp[(size_t)3 * (POS / 4)];

    #pragma unroll 1
    for (int mb = 0; mb + 4 < M_SLOTS; mb += 4) {          // mb = 0,4,...,52
        // issue next 4 loads before consuming current 4 (static offsets)
        const float4 nx0 = pp[(size_t)(mb + 4) * (POS / 4)];
        const float4 nx1 = pp[(size_t)(mb + 5) * (POS / 4)];
        const float4 nx2 = pp[(size_t)(mb + 6) * (POS / 4)];
        const float4 nx3 = pp[(size_t)(mb + 7) * (POS / 4)];
        fma_block2(acc2, s_w, mb + 0, b0, pr0);
        fma_block2(acc2, s_w, mb + 1, b0, pr1);
        fma_block2(acc2, s_w, mb + 2, b0, pr2);
        fma_block2(acc2, s_w, mb + 3, b0, pr3);
        pr0 = nx0; pr1 = nx1; pr2 = nx2; pr3 = nx3;
    }
    // tail: m = 56..59 already in the ring
    fma_block2(acc2, s_w, 56, b0, pr0);
    fma_block2(acc2, s_w, 57, b0, pr1);
    fma_block2(acc2, s_w, 58, b0, pr2);
    fma_block2(acc2, s_w, 59, b0, pr3);

    #pragma unroll
    for (int b = 0; b < B_TILE; ++b) {
        f32x4 v;
        v.x = acc2[2*b].x;   v.y = acc2[2*b].y;
        v.z = acc2[2*b+1].x; v.w = acc2[2*b+1].y;
        // nontemporal 16B store: out is write-once, don't evict pool from L3
        __builtin_nontemporal_store(v, (f32x4*)&oo[(size_t)(b0 + b) * (POS / 4)]);
    }
}

// ---------------------------------------------------------------------------
extern "C" void kernel_launch(void* const* d_in, const int* in_sizes, int n_in,
                              void* d_out, int out_size, void* d_ws, size_t ws_size,
                              hipStream_t stream) {
    const float* pool = (const float*)d_in[0];   // [60,256,56,56]
    const float* q    = (const float*)d_in[1];   // [64,256]
    float* out        = (float*)d_out;           // [64,256,56,56]

    float* sums = (float*)d_ws;                              // 60*256 floats = 61440 B
    float* wT   = (float*)((char*)d_ws + M_SLOTS * C_CH * sizeof(float));  // 60*64 floats

    avg_kernel<<<(M_SLOTS * C_CH) / 4, 256, 0, stream>>>(pool, sums);
    weights_kernel<<<B_SZ, 256, 0, stream>>>(q, sums, wT);
    wsum_kernel<<<POS / 256, 256, 0, stream>>>(pool, wT, out);
}

// Round 5
// 394.666 us; speedup vs baseline: 1.0766x; 1.0017x over previous
//
#include <hip/hip_runtime.h>
#include <math.h>

#define M_SLOTS 60
#define B_SZ    64
#define C_CH    256
#define HW      3136          // 56*56
#define POS     (C_CH * HW)   // 802816 positions per memory slot / per batch
#define EPS     1e-8f
#define B_TILE  16            // batches per wave in wsum

typedef float f32x4 __attribute__((ext_vector_type(4)));
typedef float f32x2 __attribute__((ext_vector_type(2)));

// ---------------------------------------------------------------------------
// Kernel A: per-(m,c) row sum of 3136 spatial elements. One wave per row.
// grid = 15360/4 blocks, block = 256 (4 waves, 1 row each). BW-bound ~31 us.
// Normal (caching) loads on purpose: warms L3 with pool (192.7 MB < 256 MB)
// so wsum's second pass reads from LLC instead of HBM.
// ---------------------------------------------------------------------------
__global__ __launch_bounds__(256) void avg_kernel(const float* __restrict__ pool,
                                                  float* __restrict__ sums) {
    const int row  = blockIdx.x * 4 + (threadIdx.x >> 6);  // [0, 15360)
    const int lane = threadIdx.x & 63;
    const float4* r4 = (const float4*)(pool + (size_t)row * HW);  // 12544 B rows, 16B-aligned
    float s = 0.0f;
    for (int i = lane; i < HW / 4; i += 64) {   // 784 float4 per row
        float4 v = r4[i];
        s += v.x + v.y + v.z + v.w;
    }
    #pragma unroll
    for (int off = 32; off; off >>= 1) s += __shfl_down(s, off);
    if (lane == 0) sums[row] = s;
}

// ---------------------------------------------------------------------------
// Kernel B: cosine sim + softmax. grid = 64 (one block per b), block = 256.
// Writes transposed weights wT[m*64 + b]. Tiny (~4 us).
// ---------------------------------------------------------------------------
__global__ __launch_bounds__(256) void weights_kernel(const float* __restrict__ q,
                                                      const float* __restrict__ sums,
                                                      float* __restrict__ wT) {
    const int b    = blockIdx.x;
    const int wave = threadIdx.x >> 6;
    const int lane = threadIdx.x & 63;
    const float inv = 1.0f / (float)HW;

    __shared__ float s_cos[M_SLOTS];

    // each lane holds 4 channels of q[b]; each wave computes qn redundantly (no sync needed)
    float4 qv = ((const float4*)(q + b * C_CH))[lane];
    float qn2 = qv.x*qv.x + qv.y*qv.y + qv.z*qv.z + qv.w*qv.w;
    #pragma unroll
    for (int off = 32; off; off >>= 1) qn2 += __shfl_down(qn2, off);
    qn2 = __shfl(qn2, 0);
    const float qn = fmaxf(sqrtf(qn2), EPS);

    // waves split the 60 memory slots
    for (int m = wave; m < M_SLOTS; m += 4) {
        float4 mv = ((const float4*)(sums + m * C_CH))[lane];
        mv.x *= inv; mv.y *= inv; mv.z *= inv; mv.w *= inv;
        float dot = qv.x*mv.x + qv.y*mv.y + qv.z*mv.z + qv.w*mv.w;
        float mn2 = mv.x*mv.x + mv.y*mv.y + mv.z*mv.z + mv.w*mv.w;
        #pragma unroll
        for (int off = 32; off; off >>= 1) {
            dot += __shfl_down(dot, off);
            mn2 += __shfl_down(mn2, off);
        }
        if (lane == 0) {
            float mn = fmaxf(sqrtf(mn2), EPS);
            s_cos[m] = dot / (qn * mn);
        }
    }
    __syncthreads();

    if (wave == 0) {
        float c = (lane < M_SLOTS) ? s_cos[lane] : -INFINITY;
        float mx = c;
        #pragma unroll
        for (int off = 32; off; off >>= 1) mx = fmaxf(mx, __shfl_down(mx, off));
        mx = __shfl(mx, 0);
        float e = (lane < M_SLOTS) ? __expf(c - mx) : 0.0f;
        float sum = e;
        #pragma unroll
        for (int off = 32; off; off >>= 1) sum += __shfl_down(sum, off);
        sum = __shfl(sum, 0);
        if (lane < M_SLOTS) wT[lane * B_SZ + b] = e / sum;
    }
}

// ---------------------------------------------------------------------------
// wsum inner block for one m: 16 batches x 4 positions, packed fp32 pairs.
// acc2 layout: batch b -> acc2[2b] = positions {0,1}, acc2[2b+1] = {2,3}.
// __builtin_elementwise_fma on f32x2 lowers to v_pk_fma_f32 (VOP3P):
// 32 pk-fma instead of 64 scalar fma per (m, 16 batches).
// All indices compile-time after unroll (rule #20: no scratch).
// ---------------------------------------------------------------------------
__device__ __forceinline__ void fma_block2(f32x2* acc2, const float* s_w,
                                           int m, int b0, float4 p) {
    const float4* wrow = (const float4*)(s_w + m * B_SZ + b0);   // uniform addr -> broadcast
    f32x2 p01; p01.x = p.x; p01.y = p.y;
    f32x2 p23; p23.x = p.z; p23.y = p.w;
    #pragma unroll
    for (int qq = 0; qq < 4; ++qq) {
        const float4 wv = wrow[qq];                              // ds_read_b128, conflict-free
        const int j = qq * 8;
        f32x2 w0; w0.x = wv.x; w0.y = wv.x;
        f32x2 w1; w1.x = wv.y; w1.y = wv.y;
        f32x2 w2; w2.x = wv.z; w2.y = wv.z;
        f32x2 w3; w3.x = wv.w; w3.y = wv.w;
        acc2[j+0] = __builtin_elementwise_fma(w0, p01, acc2[j+0]);
        acc2[j+1] = __builtin_elementwise_fma(w0, p23, acc2[j+1]);
        acc2[j+2] = __builtin_elementwise_fma(w1, p01, acc2[j+2]);
        acc2[j+3] = __builtin_elementwise_fma(w1, p23, acc2[j+3]);
        acc2[j+4] = __builtin_elementwise_fma(w2, p01, acc2[j+4]);
        acc2[j+5] = __builtin_elementwise_fma(w2, p23, acc2[j+5]);
        acc2[j+6] = __builtin_elementwise_fma(w3, p01, acc2[j+6]);
        acc2[j+7] = __builtin_elementwise_fma(w3, p23, acc2[j+7]);
    }
}

// ---------------------------------------------------------------------------
// Kernel C v5: weighted sum. Interleaved depth-4 rotating pipeline.
//  - __launch_bounds__(256, 4): pin VGPR <= 128 so we hold 4 waves/SIMD
//    (v4's nx[4]+pr[4] overlap pushed past 128 -> 2 waves/SIMD, latency-bound)
//  - load(m+4+k) issued immediately before fma(m+k): each load covered by
//    4 fma_blocks (~256 VALU cyc) x 4 waves/SIMD ~ 1000 cyc > L3/HBM latency
//  - only ~5 float4 pool values live at any time (20 VGPR vs v4's 32)
//  - weights staged in LDS once; uniform-address ds_read_b128 broadcasts
//  - out stored non-temporally (write-once; keep pool resident in L3)
// grid = POS/256 = 3136 blocks.
// ---------------------------------------------------------------------------
__global__ __launch_bounds__(256, 4) void wsum_kernel(const float* __restrict__ pool,
                                                      const float* __restrict__ wT,
                                                      float* __restrict__ out) {
    __shared__ float s_w[M_SLOTS * B_SZ];   // 15360 B

    for (int i = threadIdx.x; i < M_SLOTS * B_SZ; i += 256)
        s_w[i] = wT[i];
    __syncthreads();

    const int wave = threadIdx.x >> 6;
    const int lane = threadIdx.x & 63;
    const int b0   = wave * B_TILE;
    const size_t pos4 = (size_t)blockIdx.x * 64 + lane;   // float4 index within a plane
    const size_t S    = POS / 4;                          // float4 stride per m-plane

    const float4* pp = (const float4*)pool + pos4;
    float4*       oo = (float4*)out + pos4;

    f32x2 acc2[2 * B_TILE];
    #pragma unroll
    for (int j = 0; j < 2 * B_TILE; ++j) { acc2[j].x = 0.f; acc2[j].y = 0.f; }

    // prime the rotating ring (m = 0..3)
    float4 pr0 = pp[0 * S];
    float4 pr1 = pp[1 * S];
    float4 pr2 = pp[2 * S];
    float4 pr3 = pp[3 * S];

    // mb = 0,4,...,52: load m+4..m+7 one-at-a-time right before consuming m..m+3
    #pragma unroll 1
    for (int mb = 0; mb < M_SLOTS - 4; mb += 4) {
        const float4* pc = pp + (size_t)mb * S;
        float4 nx;
        nx = pc[4 * S]; fma_block2(acc2, s_w, mb + 0, b0, pr0); pr0 = nx;
        nx = pc[5 * S]; fma_block2(acc2, s_w, mb + 1, b0, pr1); pr1 = nx;
        nx = pc[6 * S]; fma_block2(acc2, s_w, mb + 2, b0, pr2); pr2 = nx;
        nx = pc[7 * S]; fma_block2(acc2, s_w, mb + 3, b0, pr3); pr3 = nx;
    }
    // tail: m = 56..59 already in the ring
    fma_block2(acc2, s_w, 56, b0, pr0);
    fma_block2(acc2, s_w, 57, b0, pr1);
    fma_block2(acc2, s_w, 58, b0, pr2);
    fma_block2(acc2, s_w, 59, b0, pr3);

    #pragma unroll
    for (int b = 0; b < B_TILE; ++b) {
        f32x4 v;
        v.x = acc2[2*b].x;   v.y = acc2[2*b].y;
        v.z = acc2[2*b+1].x; v.w = acc2[2*b+1].y;
        // nontemporal 16B store: out is write-once, don't evict pool from L3
        __builtin_nontemporal_store(v, (f32x4*)&oo[(size_t)(b0 + b) * S]);
    }
}

// ---------------------------------------------------------------------------
extern "C" void kernel_launch(void* const* d_in, const int* in_sizes, int n_in,
                              void* d_out, int out_size, void* d_ws, size_t ws_size,
                              hipStream_t stream) {
    const float* pool = (const float*)d_in[0];   // [60,256,56,56]
    const float* q    = (const float*)d_in[1];   // [64,256]
    float* out        = (float*)d_out;           // [64,256,56,56]

    float* sums = (float*)d_ws;                              // 60*256 floats = 61440 B
    float* wT   = (float*)((char*)d_ws + M_SLOTS * C_CH * sizeof(float));  // 60*64 floats

    avg_kernel<<<(M_SLOTS * C_CH) / 4, 256, 0, stream>>>(pool, sums);
    weights_kernel<<<B_SZ, 256, 0, stream>>>(q, sums, wT);
    wsum_kernel<<<POS / 256, 256, 0, stream>>>(pool, wT, out);
}

// Round 6
// 389.907 us; speedup vs baseline: 1.0898x; 1.0122x over previous
//
#include <hip/hip_runtime.h>
#include <math.h>

#define M_SLOTS 60
#define B_SZ    64
#define C_CH    256
#define HW      3136          // 56*56
#define POS     (C_CH * HW)   // 802816 positions per memory slot / per batch
#define EPS     1e-8f
#define B_TILE  16            // batches per wave in wsum

typedef float f32x4 __attribute__((ext_vector_type(4)));
typedef float f32x2 __attribute__((ext_vector_type(2)));

// ---------------------------------------------------------------------------
// Kernel A: per-(m,c) row sum of 3136 spatial elements. One wave per row.
// grid = 15360/4 blocks, block = 256 (4 waves, 1 row each). BW-bound ~31 us.
// Normal (caching) loads on purpose: warms L3 with pool (192.7 MB < 256 MB)
// so wsum's second pass reads from LLC instead of HBM.
// ---------------------------------------------------------------------------
__global__ __launch_bounds__(256) void avg_kernel(const float* __restrict__ pool,
                                                  float* __restrict__ sums) {
    const int row  = blockIdx.x * 4 + (threadIdx.x >> 6);  // [0, 15360)
    const int lane = threadIdx.x & 63;
    const float4* r4 = (const float4*)(pool + (size_t)row * HW);  // 12544 B rows, 16B-aligned
    float s = 0.0f;
    for (int i = lane; i < HW / 4; i += 64) {   // 784 float4 per row
        float4 v = r4[i];
        s += v.x + v.y + v.z + v.w;
    }
    #pragma unroll
    for (int off = 32; off; off >>= 1) s += __shfl_down(s, off);
    if (lane == 0) sums[row] = s;
}

// ---------------------------------------------------------------------------
// Kernel B: cosine sim + softmax. grid = 64 (one block per b), block = 256.
// Writes transposed weights wT[m*64 + b]. Tiny (~4 us).
// ---------------------------------------------------------------------------
__global__ __launch_bounds__(256) void weights_kernel(const float* __restrict__ q,
                                                      const float* __restrict__ sums,
                                                      float* __restrict__ wT) {
    const int b    = blockIdx.x;
    const int wave = threadIdx.x >> 6;
    const int lane = threadIdx.x & 63;
    const float inv = 1.0f / (float)HW;

    __shared__ float s_cos[M_SLOTS];

    // each lane holds 4 channels of q[b]; each wave computes qn redundantly (no sync needed)
    float4 qv = ((const float4*)(q + b * C_CH))[lane];
    float qn2 = qv.x*qv.x + qv.y*qv.y + qv.z*qv.z + qv.w*qv.w;
    #pragma unroll
    for (int off = 32; off; off >>= 1) qn2 += __shfl_down(qn2, off);
    qn2 = __shfl(qn2, 0);
    const float qn = fmaxf(sqrtf(qn2), EPS);

    // waves split the 60 memory slots
    for (int m = wave; m < M_SLOTS; m += 4) {
        float4 mv = ((const float4*)(sums + m * C_CH))[lane];
        mv.x *= inv; mv.y *= inv; mv.z *= inv; mv.w *= inv;
        float dot = qv.x*mv.x + qv.y*mv.y + qv.z*mv.z + qv.w*mv.w;
        float mn2 = mv.x*mv.x + mv.y*mv.y + mv.z*mv.z + mv.w*mv.w;
        #pragma unroll
        for (int off = 32; off; off >>= 1) {
            dot += __shfl_down(dot, off);
            mn2 += __shfl_down(mn2, off);
        }
        if (lane == 0) {
            float mn = fmaxf(sqrtf(mn2), EPS);
            s_cos[m] = dot / (qn * mn);
        }
    }
    __syncthreads();

    if (wave == 0) {
        float c = (lane < M_SLOTS) ? s_cos[lane] : -INFINITY;
        float mx = c;
        #pragma unroll
        for (int off = 32; off; off >>= 1) mx = fmaxf(mx, __shfl_down(mx, off));
        mx = __shfl(mx, 0);
        float e = (lane < M_SLOTS) ? __expf(c - mx) : 0.0f;
        float sum = e;
        #pragma unroll
        for (int off = 32; off; off >>= 1) sum += __shfl_down(sum, off);
        sum = __shfl(sum, 0);
        if (lane < M_SLOTS) wT[lane * B_SZ + b] = e / sum;
    }
}

// ---------------------------------------------------------------------------
// wsum inner block for one m: 16 batches x 4 positions, packed fp32 pairs.
// v6 change: weights read DIRECTLY from global wT with a readfirstlane-
// scalarized wave-uniform offset -> compiler can emit s_load (SMEM pipe,
// zero LDS-unit occupancy). Worst case: broadcast global_load from the
// L1-resident 15 KB wT -- ~= the ds_read it replaces.
// acc2 layout: batch b -> acc2[2b] = positions {0,1}, acc2[2b+1] = {2,3}.
// All indices compile-time after unroll (rule #20: no scratch).
// ---------------------------------------------------------------------------
__device__ __forceinline__ void fma_block2(f32x2* acc2, const float* __restrict__ wT,
                                           int m, int b0, float4 p) {
    const int off = __builtin_amdgcn_readfirstlane(m * B_SZ + b0);  // wave-uniform -> SGPR
    const float4* wrow = (const float4*)(wT + off);
    f32x2 p01; p01.x = p.x; p01.y = p.y;
    f32x2 p23; p23.x = p.z; p23.y = p.w;
    #pragma unroll
    for (int qq = 0; qq < 4; ++qq) {
        const float4 wv = wrow[qq];                  // scalar-load candidate (uniform addr)
        const int j = qq * 8;
        f32x2 w0; w0.x = wv.x; w0.y = wv.x;
        f32x2 w1; w1.x = wv.y; w1.y = wv.y;
        f32x2 w2; w2.x = wv.z; w2.y = wv.z;
        f32x2 w3; w3.x = wv.w; w3.y = wv.w;
        acc2[j+0] = __builtin_elementwise_fma(w0, p01, acc2[j+0]);
        acc2[j+1] = __builtin_elementwise_fma(w0, p23, acc2[j+1]);
        acc2[j+2] = __builtin_elementwise_fma(w1, p01, acc2[j+2]);
        acc2[j+3] = __builtin_elementwise_fma(w1, p23, acc2[j+3]);
        acc2[j+4] = __builtin_elementwise_fma(w2, p01, acc2[j+4]);
        acc2[j+5] = __builtin_elementwise_fma(w2, p23, acc2[j+5]);
        acc2[j+6] = __builtin_elementwise_fma(w3, p01, acc2[j+6]);
        acc2[j+7] = __builtin_elementwise_fma(w3, p23, acc2[j+7]);
    }
}

// ---------------------------------------------------------------------------
// Kernel C v6: weighted sum. No LDS at all.
//  - weights via scalarized direct loads (see fma_block2) -- removes the
//    240 ds_read_b128/wave that the issue-census says was the largest
//    per-CU term (~59 us > store 32 us > VALU 20 us)
//  - depth-4 rotating prefetch ring for pool (load m+4+k right before
//    consuming m+k), pk_fma, NT stores, 4 waves x 16 batches
// grid = POS/256 = 3136 blocks.
// ---------------------------------------------------------------------------
__global__ __launch_bounds__(256, 4) void wsum_kernel(const float* __restrict__ pool,
                                                      const float* __restrict__ wT,
                                                      float* __restrict__ out) {
    const int wave = threadIdx.x >> 6;
    const int lane = threadIdx.x & 63;
    const int b0   = wave * B_TILE;
    const size_t pos4 = (size_t)blockIdx.x * 64 + lane;   // float4 index within a plane
    const size_t S    = POS / 4;                          // float4 stride per m-plane

    const float4* pp = (const float4*)pool + pos4;
    float4*       oo = (float4*)out + pos4;

    f32x2 acc2[2 * B_TILE];
    #pragma unroll
    for (int j = 0; j < 2 * B_TILE; ++j) { acc2[j].x = 0.f; acc2[j].y = 0.f; }

    // prime the rotating ring (m = 0..3)
    float4 pr0 = pp[0 * S];
    float4 pr1 = pp[1 * S];
    float4 pr2 = pp[2 * S];
    float4 pr3 = pp[3 * S];

    // mb = 0,4,...,52: load m+4..m+7 one-at-a-time right before consuming m..m+3
    #pragma unroll 1
    for (int mb = 0; mb < M_SLOTS - 4; mb += 4) {
        const float4* pc = pp + (size_t)mb * S;
        float4 nx;
        nx = pc[4 * S]; fma_block2(acc2, wT, mb + 0, b0, pr0); pr0 = nx;
        nx = pc[5 * S]; fma_block2(acc2, wT, mb + 1, b0, pr1); pr1 = nx;
        nx = pc[6 * S]; fma_block2(acc2, wT, mb + 2, b0, pr2); pr2 = nx;
        nx = pc[7 * S]; fma_block2(acc2, wT, mb + 3, b0, pr3); pr3 = nx;
    }
    // tail: m = 56..59 already in the ring
    fma_block2(acc2, wT, 56, b0, pr0);
    fma_block2(acc2, wT, 57, b0, pr1);
    fma_block2(acc2, wT, 58, b0, pr2);
    fma_block2(acc2, wT, 59, b0, pr3);

    #pragma unroll
    for (int b = 0; b < B_TILE; ++b) {
        f32x4 v;
        v.x = acc2[2*b].x;   v.y = acc2[2*b].y;
        v.z = acc2[2*b+1].x; v.w = acc2[2*b+1].y;
        // nontemporal 16B store: out is write-once, don't evict pool from L3
        __builtin_nontemporal_store(v, (f32x4*)&oo[(size_t)(b0 + b) * S]);
    }
}

// ---------------------------------------------------------------------------
extern "C" void kernel_launch(void* const* d_in, const int* in_sizes, int n_in,
                              void* d_out, int out_size, void* d_ws, size_t ws_size,
                              hipStream_t stream) {
    const float* pool = (const float*)d_in[0];   // [60,256,56,56]
    const float* q    = (const float*)d_in[1];   // [64,256]
    float* out        = (float*)d_out;           // [64,256,56,56]

    float* sums = (float*)d_ws;                              // 60*256 floats = 61440 B
    float* wT   = (float*)((char*)d_ws + M_SLOTS * C_CH * sizeof(float));  // 60*64 floats

    avg_kernel<<<(M_SLOTS * C_CH) / 4, 256, 0, stream>>>(pool, sums);
    weights_kernel<<<B_SZ, 256, 0, stream>>>(q, sums, wT);
    wsum_kernel<<<POS / 256, 256, 0, stream>>>(pool, wT, out);
}